// Round 1
// baseline (23218.513 us; speedup 1.0000x reference)
//
#include <hip/hip_runtime.h>

#define N_NODES 100000
#define N_EDGES 800000
#define HIDDEN 64
#define NFP 24        // node_feat padded width (21 -> 24)
#define BLK 128

// ---------------- prep: padded We1 (rows: 3 edge + 24 src + 24 tgt) ----------------
__global__ void k_padw(const float* __restrict__ We1, float* __restrict__ We1p) {
    int i = blockIdx.x * 256 + threadIdx.x;
    if (i >= 51 * 64) return;
    int r = i >> 6, j = i & 63;
    float v;
    if (r < 3) v = We1[r * 64 + j];
    else if (r < 27) { int k = r - 3;  v = (k < 21) ? We1[(3 + k) * 64 + j] : 0.f; }
    else             { int k = r - 27; v = (k < 21) ? We1[(24 + k) * 64 + j] : 0.f; }
    We1p[i] = v;
}

// ---------------- prep: node_feat [N][24] = [h0(8), runoff[step:step+12], elev, 0,0,0] ----
__global__ void k_nf(const float* __restrict__ h0, const float* __restrict__ runoff,
                     const float* __restrict__ elev, float* __restrict__ nf, int step) {
    int i = blockIdx.x * 256 + threadIdx.x;
    if (i >= N_NODES * NFP) return;
    int n = i / NFP, c = i - n * NFP;
    float v;
    if (c < 8)        v = h0[n * 8 + c];
    else if (c < 20)  v = runoff[n * 24 + step + (c - 8)];
    else if (c == 20) v = elev[n];
    else              v = 0.f;
    nf[i] = v;
}

// ---------------- edge encoder MLP + scatter-add by src ----------------
__global__ __launch_bounds__(BLK) void k_edge_enc(
    const int* __restrict__ src_idx, const int* __restrict__ tgt_idx,
    const float* __restrict__ edge_feat, const float* __restrict__ nf,
    const float* __restrict__ We1p, const float* __restrict__ be1,
    const float* __restrict__ We2, const float* __restrict__ be2,
    float* __restrict__ coded_x) {
    __shared__ float stage[HIDDEN * BLK];
    int tid = threadIdx.x;
    int e = blockIdx.x * BLK + tid;          // grid exact: 6250*128 = 800000
    int s = src_idx[e], t = tgt_idx[e];
    float ef0 = edge_feat[e * 3], ef1 = edge_feat[e * 3 + 1], ef2 = edge_feat[e * 3 + 2];
    const float4* nfs = (const float4*)(nf + (size_t)s * NFP);
    const float4* nft = (const float4*)(nf + (size_t)t * NFP);

    float acc[64];
#pragma unroll
    for (int j = 0; j < 64; ++j)
        acc[j] = be1[j] + ef0 * We1p[j] + ef1 * We1p[64 + j] + ef2 * We1p[128 + j];

    for (int kb = 0; kb < 6; ++kb) {
        float4 vs = nfs[kb], vt = nft[kb];
        float xs[4] = {vs.x, vs.y, vs.z, vs.w};
        float xt[4] = {vt.x, vt.y, vt.z, vt.w};
        const float* w1 = We1p + (3 + kb * 4) * 64;
        const float* w2 = We1p + (27 + kb * 4) * 64;
#pragma unroll
        for (int kk = 0; kk < 4; ++kk) {
#pragma unroll
            for (int j = 0; j < 64; ++j)
                acc[j] += xs[kk] * w1[kk * 64 + j] + xt[kk] * w2[kk * 64 + j];
        }
    }
    // stage h1 = relu(acc) transposed (thread-private column tid; conflict-free)
#pragma unroll
    for (int k = 0; k < 64; ++k) stage[k * BLK + tid] = fmaxf(acc[k], 0.f);

    float acc2[64];
#pragma unroll
    for (int j = 0; j < 64; ++j) acc2[j] = be2[j];
    for (int kb = 0; kb < 16; ++kb) {
        float h[4];
#pragma unroll
        for (int kk = 0; kk < 4; ++kk) h[kk] = stage[(kb * 4 + kk) * BLK + tid];
        const float* w = We2 + kb * 4 * 64;
#pragma unroll
        for (int kk = 0; kk < 4; ++kk) {
#pragma unroll
            for (int j = 0; j < 64; ++j) acc2[j] += h[kk] * w[kk * 64 + j];
        }
    }
#pragma unroll
    for (int j = 0; j < 64; ++j) atomicAdd(&coded_x[(size_t)s * 64 + j], acc2[j]);
}

// ---------------- message MLP + scatter-add by tgt ----------------
__global__ __launch_bounds__(BLK) void k_msg(
    const int* __restrict__ src_idx, const int* __restrict__ tgt_idx,
    const float* __restrict__ coded_x,
    const float* __restrict__ Wm1, const float* __restrict__ bm1,
    const float* __restrict__ Wm2, const float* __restrict__ bm2,
    float* __restrict__ aggr) {
    __shared__ float stage[HIDDEN * BLK];
    int tid = threadIdx.x;
    int e = blockIdx.x * BLK + tid;
    int s = src_idx[e], t = tgt_idx[e];
    const float4* xsrc = (const float4*)(coded_x + (size_t)s * 64);
    const float4* xtgt = (const float4*)(coded_x + (size_t)t * 64);

    float acc[64];
#pragma unroll
    for (int j = 0; j < 64; ++j) acc[j] = bm1[j];
    for (int kb = 0; kb < 16; ++kb) {
        float4 v = xsrc[kb];
        float x[4] = {v.x, v.y, v.z, v.w};
        const float* w = Wm1 + kb * 4 * 64;
#pragma unroll
        for (int kk = 0; kk < 4; ++kk)
#pragma unroll
            for (int j = 0; j < 64; ++j) acc[j] += x[kk] * w[kk * 64 + j];
    }
    for (int kb = 0; kb < 16; ++kb) {
        float4 v = xtgt[kb];
        float x[4] = {v.x, v.y, v.z, v.w};
        const float* w = Wm1 + (64 + kb * 4) * 64;
#pragma unroll
        for (int kk = 0; kk < 4; ++kk)
#pragma unroll
            for (int j = 0; j < 64; ++j) acc[j] += x[kk] * w[kk * 64 + j];
    }
#pragma unroll
    for (int k = 0; k < 64; ++k) stage[k * BLK + tid] = fmaxf(acc[k], 0.f);

    float acc2[64];
#pragma unroll
    for (int j = 0; j < 64; ++j) acc2[j] = bm2[j];
    for (int kb = 0; kb < 16; ++kb) {
        float h[4];
#pragma unroll
        for (int kk = 0; kk < 4; ++kk) h[kk] = stage[(kb * 4 + kk) * BLK + tid];
        const float* w = Wm2 + kb * 4 * 64;
#pragma unroll
        for (int kk = 0; kk < 4; ++kk)
#pragma unroll
            for (int j = 0; j < 64; ++j) acc2[j] += h[kk] * w[kk * 64 + j];
    }
#pragma unroll
    for (int j = 0; j < 64; ++j) atomicAdd(&aggr[(size_t)t * 64 + j], acc2[j]);
}

// ---------------- node update + decoder + head + history roll ----------------
__global__ __launch_bounds__(BLK) void k_node(
    const float* __restrict__ coded_x, const float* __restrict__ aggr,
    const float* __restrict__ Wu1, const float* __restrict__ bu1,
    const float* __restrict__ Wu2, const float* __restrict__ bu2,
    const float* __restrict__ Wd1, const float* __restrict__ bd1,
    const float* __restrict__ Wd2, const float* __restrict__ bd2,
    const float* __restrict__ h0s, const float* __restrict__ elev,
    const float* __restrict__ gl,
    float* __restrict__ h0d, float* __restrict__ out, int step) {
    __shared__ float stage[HIDDEN * BLK];
    int tid = threadIdx.x;
    int n = blockIdx.x * BLK + tid;
    bool act = n < N_NODES;
    int nn = act ? n : 0;
    const float4* xc = (const float4*)(coded_x + (size_t)nn * 64);
    const float4* xa = (const float4*)(aggr + (size_t)nn * 64);

    float acc[64];
#pragma unroll
    for (int j = 0; j < 64; ++j) acc[j] = bu1[j];
    for (int kb = 0; kb < 16; ++kb) {
        float4 v = xc[kb];
        float x[4] = {v.x, v.y, v.z, v.w};
        const float* w = Wu1 + kb * 4 * 64;
#pragma unroll
        for (int kk = 0; kk < 4; ++kk)
#pragma unroll
            for (int j = 0; j < 64; ++j) acc[j] += x[kk] * w[kk * 64 + j];
    }
    for (int kb = 0; kb < 16; ++kb) {
        float4 v = xa[kb];
        float x[4] = {v.x, v.y, v.z, v.w};
        const float* w = Wu1 + (64 + kb * 4) * 64;
#pragma unroll
        for (int kk = 0; kk < 4; ++kk)
#pragma unroll
            for (int j = 0; j < 64; ++j) acc[j] += x[kk] * w[kk * 64 + j];
    }
    // stage relu(h1)
#pragma unroll
    for (int k = 0; k < 64; ++k) stage[k * BLK + tid] = fmaxf(acc[k], 0.f);
    // processed = h1 @ Wu2 + bu2 (no relu)
    float acc2[64];
#pragma unroll
    for (int j = 0; j < 64; ++j) acc2[j] = bu2[j];
    for (int kb = 0; kb < 16; ++kb) {
        float h[4];
#pragma unroll
        for (int kk = 0; kk < 4; ++kk) h[kk] = stage[(kb * 4 + kk) * BLK + tid];
        const float* w = Wu2 + kb * 4 * 64;
#pragma unroll
        for (int kk = 0; kk < 4; ++kk)
#pragma unroll
            for (int j = 0; j < 64; ++j) acc2[j] += h[kk] * w[kk * 64 + j];
    }
    // stage processed (thread-private column; sequential reuse is safe)
#pragma unroll
    for (int k = 0; k < 64; ++k) stage[k * BLK + tid] = acc2[k];
    // d1 = relu(processed @ Wd1 + bd1)
#pragma unroll
    for (int j = 0; j < 64; ++j) acc[j] = bd1[j];
    for (int kb = 0; kb < 16; ++kb) {
        float h[4];
#pragma unroll
        for (int kk = 0; kk < 4; ++kk) h[kk] = stage[(kb * 4 + kk) * BLK + tid];
        const float* w = Wd1 + kb * 4 * 64;
#pragma unroll
        for (int kk = 0; kk < 4; ++kk)
#pragma unroll
            for (int j = 0; j < 64; ++j) acc[j] += h[kk] * w[kk * 64 + j];
    }
#pragma unroll
    for (int k = 0; k < 64; ++k) stage[k * BLK + tid] = fmaxf(acc[k], 0.f);
    // decoded = d1 @ Wd2 + bd2   [4]
    float dec[4];
#pragma unroll
    for (int j = 0; j < 4; ++j) dec[j] = bd2[j];
    for (int kb = 0; kb < 16; ++kb) {
        float h[4];
#pragma unroll
        for (int kk = 0; kk < 4; ++kk) h[kk] = stage[(kb * 4 + kk) * BLK + tid];
        const float* w = Wd2 + kb * 4 * 4;
#pragma unroll
        for (int kk = 0; kk < 4; ++kk)
#pragma unroll
            for (int j = 0; j < 4; ++j) dec[j] += h[kk] * w[kk * 4 + j];
    }

    if (act) {
        float el = elev[n], g = gl[n];
        float prev = h0s[(size_t)n * 8 + 7] - el;
        float h4 = h0s[(size_t)n * 8 + 4], h5 = h0s[(size_t)n * 8 + 5],
              h6 = h0s[(size_t)n * 8 + 6], h7 = h0s[(size_t)n * 8 + 7];
        float pc[4];
#pragma unroll
        for (int j = 0; j < 4; ++j) {
            float ph = 0.5f * dec[j] + 0.5f * prev + el;
            pc[j] = fminf(ph, g);
            out[(size_t)n * 16 + step + j] = fmaxf(pc[j], el);
        }
        h0d[(size_t)n * 8 + 0] = h4;
        h0d[(size_t)n * 8 + 1] = h5;
        h0d[(size_t)n * 8 + 2] = h6;
        h0d[(size_t)n * 8 + 3] = h7;
#pragma unroll
        for (int j = 0; j < 4; ++j) h0d[(size_t)n * 8 + 4 + j] = pc[j];
    }
}

extern "C" void kernel_launch(void* const* d_in, const int* in_sizes, int n_in,
                              void* d_out, int out_size, void* d_ws, size_t ws_size,
                              hipStream_t stream) {
    const float* h0     = (const float*)d_in[0];
    const float* runoff = (const float*)d_in[1];
    const float* elev   = (const float*)d_in[2];
    const float* gl     = (const float*)d_in[3];
    const float* efeat  = (const float*)d_in[4];
    const int*   ei     = (const int*)d_in[5];   // [2, E]
    // d_in[6] = steps_ahead (16, fixed)
    const float *We1 = (const float*)d_in[7],  *be1 = (const float*)d_in[8];
    const float *We2 = (const float*)d_in[9],  *be2 = (const float*)d_in[10];
    const float *Wm1 = (const float*)d_in[11], *bm1 = (const float*)d_in[12];
    const float *Wm2 = (const float*)d_in[13], *bm2 = (const float*)d_in[14];
    const float *Wu1 = (const float*)d_in[15], *bu1 = (const float*)d_in[16];
    const float *Wu2 = (const float*)d_in[17], *bu2 = (const float*)d_in[18];
    const float *Wd1 = (const float*)d_in[19], *bd1 = (const float*)d_in[20];
    const float *Wd2 = (const float*)d_in[21], *bd2 = (const float*)d_in[22];
    float* out = (float*)d_out;

    float* ws = (float*)d_ws;
    float* We1p = ws;  ws += 51 * 64;
    float* nf   = ws;  ws += (size_t)N_NODES * NFP;
    float* cx   = ws;  ws += (size_t)N_NODES * 64;
    float* ag   = ws;  ws += (size_t)N_NODES * 64;
    float* h0A  = ws;  ws += (size_t)N_NODES * 8;
    float* h0B  = ws;  ws += (size_t)N_NODES * 8;

    const int* src = ei;
    const int* tgt = ei + N_EDGES;

    k_padw<<<13, 256, 0, stream>>>(We1, We1p);

    const float* h0rd[4] = {h0, h0A, h0B, h0A};
    float*       h0wr[4] = {h0A, h0B, h0A, h0B};

    for (int st = 0; st < 4; ++st) {
        int step = st * 4;
        k_nf<<<9375, 256, 0, stream>>>(h0rd[st], runoff, elev, nf, step);
        hipMemsetAsync(cx, 0, (size_t)N_NODES * 64 * 2 * sizeof(float), stream); // cx + ag
        k_edge_enc<<<N_EDGES / BLK, BLK, 0, stream>>>(src, tgt, efeat, nf, We1p, be1, We2, be2, cx);
        k_msg<<<N_EDGES / BLK, BLK, 0, stream>>>(src, tgt, cx, Wm1, bm1, Wm2, bm2, ag);
        k_node<<<(N_NODES + BLK - 1) / BLK, BLK, 0, stream>>>(
            cx, ag, Wu1, bu1, Wu2, bu2, Wd1, bd1, Wd2, bd2,
            h0rd[st], elev, gl, h0wr[st], out, step);
    }
}

// Round 2
// 4466.368 us; speedup vs baseline: 5.1985x; 5.1985x over previous
//
#include <hip/hip_runtime.h>

#define N_NODES 100000
#define N_EDGES 800000

// ============================ setup: CSR build ============================

__global__ __launch_bounds__(256) void k_hist(const int* __restrict__ src, const int* __restrict__ tgt,
                                              int* __restrict__ deg_src, int* __restrict__ deg_tgt) {
    int e = blockIdx.x * 256 + threadIdx.x;
    if (e >= N_EDGES) return;
    atomicAdd(&deg_src[src[e]], 1);
    atomicAdd(&deg_tgt[tgt[e]], 1);
}

__global__ __launch_bounds__(256) void k_scan1(const int* __restrict__ in, int* __restrict__ out,
                                               int* __restrict__ bsum, int n) {
    __shared__ int sm[256];
    int tid = threadIdx.x;
    int i = blockIdx.x * 256 + tid;
    int v = (i < n) ? in[i] : 0;
    int acc = v;
    sm[tid] = acc; __syncthreads();
    for (int d = 1; d < 256; d <<= 1) {
        int o = (tid >= d) ? sm[tid - d] : 0;
        __syncthreads();
        acc += o; sm[tid] = acc;
        __syncthreads();
    }
    if (i < n) out[i] = acc - v;          // exclusive
    if (tid == 255) bsum[blockIdx.x] = acc;
}

__global__ __launch_bounds__(512) void k_scan_top(int* __restrict__ a, int n) {
    __shared__ int sm[512];
    int tid = threadIdx.x;
    int v = (tid < n) ? a[tid] : 0;
    int acc = v;
    sm[tid] = acc; __syncthreads();
    for (int d = 1; d < 512; d <<= 1) {
        int o = (tid >= d) ? sm[tid - d] : 0;
        __syncthreads();
        acc += o; sm[tid] = acc;
        __syncthreads();
    }
    if (tid < n) a[tid] = acc - v;        // exclusive in place
}

__global__ __launch_bounds__(256) void k_scan_add(int* __restrict__ out, const int* __restrict__ bsum, int n) {
    int i = blockIdx.x * 256 + threadIdx.x;
    if (i < n) out[i] += bsum[blockIdx.x];
}

__global__ __launch_bounds__(256) void k_fill(const int* __restrict__ src, const int* __restrict__ tgt,
                                              const int* __restrict__ off_src, const int* __restrict__ off_tgt,
                                              int* __restrict__ cur_src, int* __restrict__ cur_tgt,
                                              int* __restrict__ perm_src, int* __restrict__ perm_tgt) {
    int e = blockIdx.x * 256 + threadIdx.x;
    if (e >= N_EDGES) return;
    int s = src[e], t = tgt[e];
    perm_src[off_src[s] + atomicAdd(&cur_src[s], 1)] = e;
    perm_tgt[off_tgt[t] + atomicAdd(&cur_tgt[t], 1)] = e;
}

__global__ __launch_bounds__(256) void k_hist_deg(const int* __restrict__ deg_src, const int* __restrict__ deg_tgt,
                                                  int* __restrict__ dhist) {
    int n = blockIdx.x * 256 + threadIdx.x;
    if (n >= N_NODES) return;
    int b1 = deg_src[n]; b1 = b1 > 63 ? 63 : b1;
    int b2 = deg_tgt[n]; b2 = b2 > 63 ? 63 : b2;
    atomicAdd(&dhist[b1], 1);
    atomicAdd(&dhist[64 + b2], 1);
}

__global__ __launch_bounds__(64) void k_scan_small(const int* __restrict__ in, int* __restrict__ out) {
    __shared__ int sm[64];
    int tid = threadIdx.x;
    const int* a = in + blockIdx.x * 64;
    int v = a[tid];
    int acc = v;
    sm[tid] = acc; __syncthreads();
    for (int d = 1; d < 64; d <<= 1) {
        int o = (tid >= d) ? sm[tid - d] : 0;
        __syncthreads();
        acc += o; sm[tid] = acc;
        __syncthreads();
    }
    out[blockIdx.x * 64 + tid] = acc - v;
}

__global__ __launch_bounds__(256) void k_fill_order(const int* __restrict__ deg_src, const int* __restrict__ deg_tgt,
                                                    const int* __restrict__ doff, int* __restrict__ dcur,
                                                    int* __restrict__ order_src, int* __restrict__ order_tgt) {
    int n = blockIdx.x * 256 + threadIdx.x;
    if (n >= N_NODES) return;
    int b1 = deg_src[n]; b1 = b1 > 63 ? 63 : b1;
    int b2 = deg_tgt[n]; b2 = b2 > 63 ? 63 : b2;
    order_src[doff[b1] + atomicAdd(&dcur[b1], 1)] = n;
    order_tgt[doff[64 + b2] + atomicAdd(&dcur[64 + b2], 1)] = n;
}

// ============================ per-step kernels ============================

// S[n] = nf[n] @ We1[3:24], T[n] = nf[n] @ We1[24:45]; nf built in registers.
__global__ __launch_bounds__(256) void k_pre_enc(const float* __restrict__ h0, const float* __restrict__ runoff,
                                                 const float* __restrict__ elev, const float* __restrict__ We1,
                                                 float* __restrict__ S, float* __restrict__ T, int step) {
    int n = blockIdx.x * 256 + threadIdx.x;
    if (n >= N_NODES) return;
    float x[21];
    const float4* h4 = (const float4*)(h0 + (size_t)n * 8);
    float4 a = h4[0], b = h4[1];
    x[0] = a.x; x[1] = a.y; x[2] = a.z; x[3] = a.w;
    x[4] = b.x; x[5] = b.y; x[6] = b.z; x[7] = b.w;
    const float4* r4 = (const float4*)(runoff + (size_t)n * 24 + step);
    float4 r0 = r4[0], r1 = r4[1], r2 = r4[2];
    x[8] = r0.x;  x[9] = r0.y;  x[10] = r0.z; x[11] = r0.w;
    x[12] = r1.x; x[13] = r1.y; x[14] = r1.z; x[15] = r1.w;
    x[16] = r2.x; x[17] = r2.y; x[18] = r2.z; x[19] = r2.w;
    x[20] = elev[n];
    for (int jq = 0; jq < 16; ++jq) {
        float s0 = 0, s1 = 0, s2 = 0, s3 = 0, t0 = 0, t1 = 0, t2 = 0, t3 = 0;
#pragma unroll
        for (int k = 0; k < 21; ++k) {
            float xv = x[k];
            const float* wS = We1 + (3 + k) * 64 + jq * 4;
            const float* wT = We1 + (24 + k) * 64 + jq * 4;
            s0 += xv * wS[0]; s1 += xv * wS[1]; s2 += xv * wS[2]; s3 += xv * wS[3];
            t0 += xv * wT[0]; t1 += xv * wT[1]; t2 += xv * wT[2]; t3 += xv * wT[3];
        }
        *(float4*)(S + (size_t)n * 64 + jq * 4) = make_float4(s0, s1, s2, s3);
        *(float4*)(T + (size_t)n * 64 + jq * 4) = make_float4(t0, t1, t2, t3);
    }
}

// coded_x[n] = sum_{e: src=n} ( relu(ef@We_e + S[n] + T[tgt] + be1) @ We2 + be2 )
__global__ __launch_bounds__(256) void k_agg_src(
    const int* __restrict__ order, const int* __restrict__ deg, const int* __restrict__ off,
    const int* __restrict__ perm, const int* __restrict__ tgt_idx, const float* __restrict__ edge_feat,
    const float* __restrict__ S, const float* __restrict__ T,
    const float* __restrict__ We1, const float* __restrict__ be1,
    const float* __restrict__ We2, const float* __restrict__ be2,
    float* __restrict__ coded_x) {
    int i = blockIdx.x * 256 + threadIdx.x;
    if (i >= N_NODES) return;
    int n = order[i];
    int d = deg[n], base = off[n];
    float acc[64];
#pragma unroll
    for (int j = 0; j < 64; ++j) acc[j] = 0.f;
    const float4* S4 = (const float4*)(S + (size_t)n * 64);
    for (int p = 0; p < d; ++p) {
        int e = perm[base + p];
        int t = tgt_idx[e];
        float ef0 = edge_feat[3 * e], ef1 = edge_feat[3 * e + 1], ef2 = edge_feat[3 * e + 2];
        const float4* T4 = (const float4*)(T + (size_t)t * 64);
        for (int kb = 0; kb < 16; ++kb) {
            float4 sv = S4[kb], tv = T4[kb];
            float sr[4] = {sv.x, sv.y, sv.z, sv.w};
            float tr[4] = {tv.x, tv.y, tv.z, tv.w};
            float h[4];
#pragma unroll
            for (int kk = 0; kk < 4; ++kk) {
                int k = kb * 4 + kk;
                float v = be1[k] + ef0 * We1[k] + ef1 * We1[64 + k] + ef2 * We1[128 + k] + sr[kk] + tr[kk];
                h[kk] = fmaxf(v, 0.f);
            }
            const float* w = We2 + kb * 256;
#pragma unroll
            for (int kk = 0; kk < 4; ++kk)
#pragma unroll
                for (int j = 0; j < 64; ++j) acc[j] += h[kk] * w[kk * 64 + j];
        }
    }
    float dd = (float)d;
    float4* o4 = (float4*)(coded_x + (size_t)n * 64);
#pragma unroll
    for (int jq = 0; jq < 16; ++jq)
        o4[jq] = make_float4(acc[jq * 4 + 0] + dd * be2[jq * 4 + 0],
                             acc[jq * 4 + 1] + dd * be2[jq * 4 + 1],
                             acc[jq * 4 + 2] + dd * be2[jq * 4 + 2],
                             acc[jq * 4 + 3] + dd * be2[jq * 4 + 3]);
}

// A[n] = cx[n] @ Wm1[0:64], B[n] = cx[n] @ Wm1[64:128]
__global__ __launch_bounds__(256) void k_pre_msg(const float* __restrict__ cx, const float* __restrict__ Wm1,
                                                 float* __restrict__ A, float* __restrict__ B) {
    int n = blockIdx.x * 256 + threadIdx.x;
    if (n >= N_NODES) return;
    const float4* x4 = (const float4*)(cx + (size_t)n * 64);
    float acc[64];
#pragma unroll
    for (int j = 0; j < 64; ++j) acc[j] = 0.f;
    for (int kb = 0; kb < 16; ++kb) {
        float4 v = x4[kb];
        float xr[4] = {v.x, v.y, v.z, v.w};
        const float* w = Wm1 + kb * 256;
#pragma unroll
        for (int kk = 0; kk < 4; ++kk)
#pragma unroll
            for (int j = 0; j < 64; ++j) acc[j] += xr[kk] * w[kk * 64 + j];
    }
    float4* oA = (float4*)(A + (size_t)n * 64);
#pragma unroll
    for (int jq = 0; jq < 16; ++jq)
        oA[jq] = make_float4(acc[jq * 4], acc[jq * 4 + 1], acc[jq * 4 + 2], acc[jq * 4 + 3]);
#pragma unroll
    for (int j = 0; j < 64; ++j) acc[j] = 0.f;
    for (int kb = 0; kb < 16; ++kb) {
        float4 v = x4[kb];
        float xr[4] = {v.x, v.y, v.z, v.w};
        const float* w = Wm1 + 4096 + kb * 256;
#pragma unroll
        for (int kk = 0; kk < 4; ++kk)
#pragma unroll
            for (int j = 0; j < 64; ++j) acc[j] += xr[kk] * w[kk * 64 + j];
    }
    float4* oB = (float4*)(B + (size_t)n * 64);
#pragma unroll
    for (int jq = 0; jq < 16; ++jq)
        oB[jq] = make_float4(acc[jq * 4], acc[jq * 4 + 1], acc[jq * 4 + 2], acc[jq * 4 + 3]);
}

// aggr[n] = sum_{e: tgt=n} ( relu(A[src] + B[n] + bm1) @ Wm2 + bm2 )
__global__ __launch_bounds__(256) void k_agg_tgt(
    const int* __restrict__ order, const int* __restrict__ deg, const int* __restrict__ off,
    const int* __restrict__ perm, const int* __restrict__ src_idx,
    const float* __restrict__ A, const float* __restrict__ B,
    const float* __restrict__ bm1, const float* __restrict__ Wm2, const float* __restrict__ bm2,
    float* __restrict__ aggr) {
    int i = blockIdx.x * 256 + threadIdx.x;
    if (i >= N_NODES) return;
    int n = order[i];
    int d = deg[n], base = off[n];
    float acc[64];
#pragma unroll
    for (int j = 0; j < 64; ++j) acc[j] = 0.f;
    const float4* B4 = (const float4*)(B + (size_t)n * 64);
    for (int p = 0; p < d; ++p) {
        int e = perm[base + p];
        int s = src_idx[e];
        const float4* A4 = (const float4*)(A + (size_t)s * 64);
        for (int kb = 0; kb < 16; ++kb) {
            float4 av = A4[kb], bv = B4[kb];
            float ar[4] = {av.x, av.y, av.z, av.w};
            float br[4] = {bv.x, bv.y, bv.z, bv.w};
            float h[4];
#pragma unroll
            for (int kk = 0; kk < 4; ++kk)
                h[kk] = fmaxf(bm1[kb * 4 + kk] + ar[kk] + br[kk], 0.f);
            const float* w = Wm2 + kb * 256;
#pragma unroll
            for (int kk = 0; kk < 4; ++kk)
#pragma unroll
                for (int j = 0; j < 64; ++j) acc[j] += h[kk] * w[kk * 64 + j];
        }
    }
    float dd = (float)d;
    float4* o4 = (float4*)(aggr + (size_t)n * 64);
#pragma unroll
    for (int jq = 0; jq < 16; ++jq)
        o4[jq] = make_float4(acc[jq * 4 + 0] + dd * bm2[jq * 4 + 0],
                             acc[jq * 4 + 1] + dd * bm2[jq * 4 + 1],
                             acc[jq * 4 + 2] + dd * bm2[jq * 4 + 2],
                             acc[jq * 4 + 3] + dd * bm2[jq * 4 + 3]);
}

// ---------------- node update + decoder + head + history roll (unchanged) ----------------
#define BLK 128
__global__ __launch_bounds__(BLK) void k_node(
    const float* __restrict__ coded_x, const float* __restrict__ aggr,
    const float* __restrict__ Wu1, const float* __restrict__ bu1,
    const float* __restrict__ Wu2, const float* __restrict__ bu2,
    const float* __restrict__ Wd1, const float* __restrict__ bd1,
    const float* __restrict__ Wd2, const float* __restrict__ bd2,
    const float* __restrict__ h0s, const float* __restrict__ elev,
    const float* __restrict__ gl,
    float* __restrict__ h0d, float* __restrict__ out, int step) {
    __shared__ float stage[64 * BLK];
    int tid = threadIdx.x;
    int n = blockIdx.x * BLK + tid;
    bool act = n < N_NODES;
    int nn = act ? n : 0;
    const float4* xc = (const float4*)(coded_x + (size_t)nn * 64);
    const float4* xa = (const float4*)(aggr + (size_t)nn * 64);

    float acc[64];
#pragma unroll
    for (int j = 0; j < 64; ++j) acc[j] = bu1[j];
    for (int kb = 0; kb < 16; ++kb) {
        float4 v = xc[kb];
        float x[4] = {v.x, v.y, v.z, v.w};
        const float* w = Wu1 + kb * 4 * 64;
#pragma unroll
        for (int kk = 0; kk < 4; ++kk)
#pragma unroll
            for (int j = 0; j < 64; ++j) acc[j] += x[kk] * w[kk * 64 + j];
    }
    for (int kb = 0; kb < 16; ++kb) {
        float4 v = xa[kb];
        float x[4] = {v.x, v.y, v.z, v.w};
        const float* w = Wu1 + (64 + kb * 4) * 64;
#pragma unroll
        for (int kk = 0; kk < 4; ++kk)
#pragma unroll
            for (int j = 0; j < 64; ++j) acc[j] += x[kk] * w[kk * 64 + j];
    }
#pragma unroll
    for (int k = 0; k < 64; ++k) stage[k * BLK + tid] = fmaxf(acc[k], 0.f);

    float acc2[64];
#pragma unroll
    for (int j = 0; j < 64; ++j) acc2[j] = bu2[j];
    for (int kb = 0; kb < 16; ++kb) {
        float h[4];
#pragma unroll
        for (int kk = 0; kk < 4; ++kk) h[kk] = stage[(kb * 4 + kk) * BLK + tid];
        const float* w = Wu2 + kb * 4 * 64;
#pragma unroll
        for (int kk = 0; kk < 4; ++kk)
#pragma unroll
            for (int j = 0; j < 64; ++j) acc2[j] += h[kk] * w[kk * 64 + j];
    }
#pragma unroll
    for (int k = 0; k < 64; ++k) stage[k * BLK + tid] = acc2[k];
#pragma unroll
    for (int j = 0; j < 64; ++j) acc[j] = bd1[j];
    for (int kb = 0; kb < 16; ++kb) {
        float h[4];
#pragma unroll
        for (int kk = 0; kk < 4; ++kk) h[kk] = stage[(kb * 4 + kk) * BLK + tid];
        const float* w = Wd1 + kb * 4 * 64;
#pragma unroll
        for (int kk = 0; kk < 4; ++kk)
#pragma unroll
            for (int j = 0; j < 64; ++j) acc[j] += h[kk] * w[kk * 64 + j];
    }
#pragma unroll
    for (int k = 0; k < 64; ++k) stage[k * BLK + tid] = fmaxf(acc[k], 0.f);
    float dec[4];
#pragma unroll
    for (int j = 0; j < 4; ++j) dec[j] = bd2[j];
    for (int kb = 0; kb < 16; ++kb) {
        float h[4];
#pragma unroll
        for (int kk = 0; kk < 4; ++kk) h[kk] = stage[(kb * 4 + kk) * BLK + tid];
        const float* w = Wd2 + kb * 4 * 4;
#pragma unroll
        for (int kk = 0; kk < 4; ++kk)
#pragma unroll
            for (int j = 0; j < 4; ++j) dec[j] += h[kk] * w[kk * 4 + j];
    }

    if (act) {
        float el = elev[n], g = gl[n];
        float prev = h0s[(size_t)n * 8 + 7] - el;
        float h4 = h0s[(size_t)n * 8 + 4], h5 = h0s[(size_t)n * 8 + 5],
              h6 = h0s[(size_t)n * 8 + 6], h7 = h0s[(size_t)n * 8 + 7];
        float pc[4];
#pragma unroll
        for (int j = 0; j < 4; ++j) {
            float ph = 0.5f * dec[j] + 0.5f * prev + el;
            pc[j] = fminf(ph, g);
            out[(size_t)n * 16 + step + j] = fmaxf(pc[j], el);
        }
        h0d[(size_t)n * 8 + 0] = h4;
        h0d[(size_t)n * 8 + 1] = h5;
        h0d[(size_t)n * 8 + 2] = h6;
        h0d[(size_t)n * 8 + 3] = h7;
#pragma unroll
        for (int j = 0; j < 4; ++j) h0d[(size_t)n * 8 + 4 + j] = pc[j];
    }
}

extern "C" void kernel_launch(void* const* d_in, const int* in_sizes, int n_in,
                              void* d_out, int out_size, void* d_ws, size_t ws_size,
                              hipStream_t stream) {
    const float* h0     = (const float*)d_in[0];
    const float* runoff = (const float*)d_in[1];
    const float* elev   = (const float*)d_in[2];
    const float* gl     = (const float*)d_in[3];
    const float* efeat  = (const float*)d_in[4];
    const int*   ei     = (const int*)d_in[5];
    const float *We1 = (const float*)d_in[7],  *be1 = (const float*)d_in[8];
    const float *We2 = (const float*)d_in[9],  *be2 = (const float*)d_in[10];
    const float *Wm1 = (const float*)d_in[11], *bm1 = (const float*)d_in[12];
    const float *Wm2 = (const float*)d_in[13], *bm2 = (const float*)d_in[14];
    const float *Wu1 = (const float*)d_in[15], *bu1 = (const float*)d_in[16];
    const float *Wu2 = (const float*)d_in[17], *bu2 = (const float*)d_in[18];
    const float *Wd1 = (const float*)d_in[19], *bd1 = (const float*)d_in[20];
    const float *Wd2 = (const float*)d_in[21], *bd2 = (const float*)d_in[22];
    float* out = (float*)d_out;

    // ---- workspace layout ----
    float* F = (float*)d_ws;
    float* S   = F;                     // 100k*64  (reused as A)
    float* T   = S + 6400000;           // 100k*64  (reused as B)
    float* cx  = T + 6400000;
    float* ag  = cx + 6400000;
    float* h0A = ag + 6400000;
    float* h0B = h0A + 800000;
    int* I = (int*)(h0B + 800000);
    int* deg_src  = I;
    int* deg_tgt  = I + 100000;
    int* cur_src  = I + 200000;
    int* cur_tgt  = I + 300000;
    int* dhist    = I + 400000;         // 128
    int* dcur     = I + 400128;         // 128
    int* off_src  = I + 400256;
    int* off_tgt  = I + 500256;
    int* doff     = I + 600256;         // 128
    int* perm_src = I + 600384;
    int* perm_tgt = I + 1400384;
    int* order_src= I + 2200384;
    int* order_tgt= I + 2300384;
    int* bsum     = I + 2400384;        // 512

    const int* src = ei;
    const int* tgt = ei + N_EDGES;

    // ---- once per launch: CSR + degree-sorted orders ----
    hipMemsetAsync(I, 0, (size_t)400256 * sizeof(int), stream);   // deg,cur,dhist,dcur
    k_hist<<<(N_EDGES + 255) / 256, 256, 0, stream>>>(src, tgt, deg_src, deg_tgt);

    int nb = (N_NODES + 255) / 256;    // 391
    k_scan1<<<nb, 256, 0, stream>>>(deg_src, off_src, bsum, N_NODES);
    k_scan_top<<<1, 512, 0, stream>>>(bsum, nb);
    k_scan_add<<<nb, 256, 0, stream>>>(off_src, bsum, N_NODES);
    k_scan1<<<nb, 256, 0, stream>>>(deg_tgt, off_tgt, bsum, N_NODES);
    k_scan_top<<<1, 512, 0, stream>>>(bsum, nb);
    k_scan_add<<<nb, 256, 0, stream>>>(off_tgt, bsum, N_NODES);

    k_fill<<<(N_EDGES + 255) / 256, 256, 0, stream>>>(src, tgt, off_src, off_tgt,
                                                      cur_src, cur_tgt, perm_src, perm_tgt);
    k_hist_deg<<<nb, 256, 0, stream>>>(deg_src, deg_tgt, dhist);
    k_scan_small<<<2, 64, 0, stream>>>(dhist, doff);
    k_fill_order<<<nb, 256, 0, stream>>>(deg_src, deg_tgt, doff, dcur, order_src, order_tgt);

    // ---- 4 prediction steps ----
    const float* h0rd[4] = {h0, h0A, h0B, h0A};
    float*       h0wr[4] = {h0A, h0B, h0A, h0B};

    for (int st = 0; st < 4; ++st) {
        int step = st * 4;
        k_pre_enc<<<nb, 256, 0, stream>>>(h0rd[st], runoff, elev, We1, S, T, step);
        k_agg_src<<<nb, 256, 0, stream>>>(order_src, deg_src, off_src, perm_src, tgt, efeat,
                                          S, T, We1, be1, We2, be2, cx);
        k_pre_msg<<<nb, 256, 0, stream>>>(cx, Wm1, S, T);   // S=A, T=B (reuse)
        k_agg_tgt<<<nb, 256, 0, stream>>>(order_tgt, deg_tgt, off_tgt, perm_tgt, src,
                                          S, T, bm1, Wm2, bm2, ag);
        k_node<<<(N_NODES + BLK - 1) / BLK, BLK, 0, stream>>>(
            cx, ag, Wu1, bu1, Wu2, bu2, Wd1, bd1, Wd2, bd2,
            h0rd[st], elev, gl, h0wr[st], out, step);
    }
}

// Round 5
// 4318.629 us; speedup vs baseline: 5.3764x; 1.0342x over previous
//
#include <hip/hip_runtime.h>

#define N_NODES 100000
#define N_EDGES 800000

// ============================ setup: CSR build ============================

__global__ __launch_bounds__(256) void k_hist(const int* __restrict__ src, const int* __restrict__ tgt,
                                              int* __restrict__ deg_src, int* __restrict__ deg_tgt) {
    int e = blockIdx.x * 256 + threadIdx.x;
    if (e >= N_EDGES) return;
    atomicAdd(&deg_src[src[e]], 1);
    atomicAdd(&deg_tgt[tgt[e]], 1);
}

__global__ __launch_bounds__(256) void k_scan1(const int* __restrict__ in, int* __restrict__ out,
                                               int* __restrict__ bsum, int n) {
    __shared__ int sm[256];
    int tid = threadIdx.x;
    int i = blockIdx.x * 256 + tid;
    int v = (i < n) ? in[i] : 0;
    int acc = v;
    sm[tid] = acc; __syncthreads();
    for (int d = 1; d < 256; d <<= 1) {
        int o = (tid >= d) ? sm[tid - d] : 0;
        __syncthreads();
        acc += o; sm[tid] = acc;
        __syncthreads();
    }
    if (i < n) out[i] = acc - v;          // exclusive
    if (tid == 255) bsum[blockIdx.x] = acc;
}

__global__ __launch_bounds__(512) void k_scan_top(int* __restrict__ a, int n) {
    __shared__ int sm[512];
    int tid = threadIdx.x;
    int v = (tid < n) ? a[tid] : 0;
    int acc = v;
    sm[tid] = acc; __syncthreads();
    for (int d = 1; d < 512; d <<= 1) {
        int o = (tid >= d) ? sm[tid - d] : 0;
        __syncthreads();
        acc += o; sm[tid] = acc;
        __syncthreads();
    }
    if (tid < n) a[tid] = acc - v;        // exclusive in place
}

__global__ __launch_bounds__(256) void k_scan_add(int* __restrict__ out, const int* __restrict__ bsum, int n) {
    int i = blockIdx.x * 256 + threadIdx.x;
    if (i < n) out[i] += bsum[blockIdx.x];
}

__global__ __launch_bounds__(256) void k_fill(const int* __restrict__ src, const int* __restrict__ tgt,
                                              const int* __restrict__ off_src, const int* __restrict__ off_tgt,
                                              int* __restrict__ cur_src, int* __restrict__ cur_tgt,
                                              int* __restrict__ perm_src, int* __restrict__ perm_tgt) {
    int e = blockIdx.x * 256 + threadIdx.x;
    if (e >= N_EDGES) return;
    int s = src[e], t = tgt[e];
    perm_src[off_src[s] + atomicAdd(&cur_src[s], 1)] = e;
    perm_tgt[off_tgt[t] + atomicAdd(&cur_tgt[t], 1)] = e;
}

// per-block degree-bin histograms (LDS only; no global atomics)
__global__ __launch_bounds__(256) void k_blockhist(const int* __restrict__ deg_src, const int* __restrict__ deg_tgt,
                                                   int* __restrict__ bh) {
    __shared__ int h[128];
    int tid = threadIdx.x;
    if (tid < 128) h[tid] = 0;
    __syncthreads();
    int n = blockIdx.x * 256 + tid;
    if (n < N_NODES) {
        int b1 = min(deg_src[n], 63), b2 = min(deg_tgt[n], 63);
        atomicAdd(&h[b1], 1);
        atomicAdd(&h[64 + b2], 1);
    }
    __syncthreads();
    if (tid < 128) bh[blockIdx.x * 128 + tid] = h[tid];
}

// per-bin exclusive scan over blocks (in place) + per-side exclusive scan of bin totals -> doff
__global__ __launch_bounds__(128) void k_binscan(int* __restrict__ bh, int* __restrict__ doff, int nb) {
    __shared__ int sm[128];
    int tid = threadIdx.x;
    int acc = 0;
    for (int b = 0; b < nb; ++b) {
        int v = bh[b * 128 + tid];
        bh[b * 128 + tid] = acc;
        acc += v;
    }
    sm[tid] = acc; __syncthreads();
    int s = acc;
    for (int dd = 1; dd < 64; dd <<= 1) {
        int o = ((tid & 63) >= dd) ? sm[tid - dd] : 0;
        __syncthreads();
        s += o; sm[tid] = s;
        __syncthreads();
    }
    doff[tid] = s - acc;                  // exclusive within each side
}

__global__ __launch_bounds__(256) void k_fill_order2(const int* __restrict__ deg_src, const int* __restrict__ deg_tgt,
                                                     const int* __restrict__ bh, const int* __restrict__ doff,
                                                     int* __restrict__ order_src, int* __restrict__ order_tgt) {
    __shared__ int h[128];
    int tid = threadIdx.x;
    if (tid < 128) h[tid] = 0;
    __syncthreads();
    int n = blockIdx.x * 256 + tid;
    if (n < N_NODES) {
        int b1 = min(deg_src[n], 63), b2 = min(deg_tgt[n], 63);
        int r1 = atomicAdd(&h[b1], 1);
        int r2 = atomicAdd(&h[64 + b2], 1);
        order_src[doff[b1] + bh[blockIdx.x * 128 + b1] + r1] = n;
        order_tgt[doff[64 + b2] + bh[blockIdx.x * 128 + 64 + b2] + r2] = n;
    }
}

// ============================ per-step kernels ============================

// S[n] = nf[n] @ We1[3:24], T[n] = nf[n] @ We1[24:45]; nf built in registers.
__global__ __launch_bounds__(256) void k_pre_enc(const float* __restrict__ h0, const float* __restrict__ runoff,
                                                 const float* __restrict__ elev, const float* __restrict__ We1,
                                                 float* __restrict__ S, float* __restrict__ T, int step) {
    int n = blockIdx.x * 256 + threadIdx.x;
    if (n >= N_NODES) return;
    float x[21];
    const float4* h4 = (const float4*)(h0 + (size_t)n * 8);
    float4 a = h4[0], b = h4[1];
    x[0] = a.x; x[1] = a.y; x[2] = a.z; x[3] = a.w;
    x[4] = b.x; x[5] = b.y; x[6] = b.z; x[7] = b.w;
    const float4* r4 = (const float4*)(runoff + (size_t)n * 24 + step);
    float4 r0 = r4[0], r1 = r4[1], r2 = r4[2];
    x[8] = r0.x;  x[9] = r0.y;  x[10] = r0.z; x[11] = r0.w;
    x[12] = r1.x; x[13] = r1.y; x[14] = r1.z; x[15] = r1.w;
    x[16] = r2.x; x[17] = r2.y; x[18] = r2.z; x[19] = r2.w;
    x[20] = elev[n];
    for (int jq = 0; jq < 16; ++jq) {
        float s0 = 0, s1 = 0, s2 = 0, s3 = 0, t0 = 0, t1 = 0, t2 = 0, t3 = 0;
#pragma unroll
        for (int k = 0; k < 21; ++k) {
            float xv = x[k];
            const float* wS = We1 + (3 + k) * 64 + jq * 4;
            const float* wT = We1 + (24 + k) * 64 + jq * 4;
            s0 += xv * wS[0]; s1 += xv * wS[1]; s2 += xv * wS[2]; s3 += xv * wS[3];
            t0 += xv * wT[0]; t1 += xv * wT[1]; t2 += xv * wT[2]; t3 += xv * wT[3];
        }
        *(float4*)(S + (size_t)n * 64 + jq * 4) = make_float4(s0, s1, s2, s3);
        *(float4*)(T + (size_t)n * 64 + jq * 4) = make_float4(t0, t1, t2, t3);
    }
}

// coded_x[n] = sum_{e: src=n} ( relu(ef@We_e + S[n] + T[tgt] + be1) @ We2 + be2 )
// 4 lanes per node; each walks every 4th CSR edge; shfl butterfly combines.
__global__ __launch_bounds__(256) void k_agg_src(
    const int* __restrict__ order, const int* __restrict__ deg, const int* __restrict__ off,
    const int* __restrict__ perm, const int* __restrict__ tgt_idx, const float* __restrict__ edge_feat,
    const float* __restrict__ S, const float* __restrict__ T,
    const float* __restrict__ We1, const float* __restrict__ be1,
    const float* __restrict__ We2, const float* __restrict__ be2,
    float* __restrict__ coded_x) {
    int i = blockIdx.x * 256 + threadIdx.x;
    if (i >= 4 * N_NODES) return;         // inactive threads form whole quads
    int q = i & 3;
    int n = order[i >> 2];
    int d = deg[n], base = off[n];
    float acc[64];
#pragma unroll
    for (int j = 0; j < 64; ++j) acc[j] = 0.f;
    const float4* S4 = (const float4*)(S + (size_t)n * 64);
    for (int p = q; p < d; p += 4) {
        int e = perm[base + p];
        int t = tgt_idx[e];
        float ef0 = edge_feat[3 * e], ef1 = edge_feat[3 * e + 1], ef2 = edge_feat[3 * e + 2];
        const float4* T4 = (const float4*)(T + (size_t)t * 64);
#pragma unroll
        for (int kb = 0; kb < 16; ++kb) {
            float4 sv = S4[kb], tv = T4[kb];
            float sr[4] = {sv.x, sv.y, sv.z, sv.w};
            float tr[4] = {tv.x, tv.y, tv.z, tv.w};
            float h[4];
#pragma unroll
            for (int kk = 0; kk < 4; ++kk) {
                int k = kb * 4 + kk;
                h[kk] = fmaxf(be1[k] + ef0 * We1[k] + ef1 * We1[64 + k] + ef2 * We1[128 + k] + sr[kk] + tr[kk], 0.f);
            }
            const float* w = We2 + kb * 256;
#pragma unroll
            for (int kk = 0; kk < 4; ++kk)
#pragma unroll
                for (int j = 0; j < 64; ++j) acc[j] += h[kk] * w[kk * 64 + j];
        }
    }
#pragma unroll
    for (int j = 0; j < 64; ++j) {
        float v = acc[j];
        v += __shfl_xor(v, 1);
        v += __shfl_xor(v, 2);
        acc[j] = v;
    }
    if (q == 0) {
        float dd = (float)d;
        float4* o4 = (float4*)(coded_x + (size_t)n * 64);
#pragma unroll
        for (int jq = 0; jq < 16; ++jq)
            o4[jq] = make_float4(acc[jq * 4 + 0] + dd * be2[jq * 4 + 0],
                                 acc[jq * 4 + 1] + dd * be2[jq * 4 + 1],
                                 acc[jq * 4 + 2] + dd * be2[jq * 4 + 2],
                                 acc[jq * 4 + 3] + dd * be2[jq * 4 + 3]);
    }
}

// A[n] = cx[n] @ Wm1[0:64], B[n] = cx[n] @ Wm1[64:128]
__global__ __launch_bounds__(256) void k_pre_msg(const float* __restrict__ cx, const float* __restrict__ Wm1,
                                                 float* __restrict__ A, float* __restrict__ B) {
    int n = blockIdx.x * 256 + threadIdx.x;
    if (n >= N_NODES) return;
    const float4* x4 = (const float4*)(cx + (size_t)n * 64);
    float acc[64];
#pragma unroll
    for (int j = 0; j < 64; ++j) acc[j] = 0.f;
    for (int kb = 0; kb < 16; ++kb) {
        float4 v = x4[kb];
        float xr[4] = {v.x, v.y, v.z, v.w};
        const float* w = Wm1 + kb * 256;
#pragma unroll
        for (int kk = 0; kk < 4; ++kk)
#pragma unroll
            for (int j = 0; j < 64; ++j) acc[j] += xr[kk] * w[kk * 64 + j];
    }
    float4* oA = (float4*)(A + (size_t)n * 64);
#pragma unroll
    for (int jq = 0; jq < 16; ++jq)
        oA[jq] = make_float4(acc[jq * 4], acc[jq * 4 + 1], acc[jq * 4 + 2], acc[jq * 4 + 3]);
#pragma unroll
    for (int j = 0; j < 64; ++j) acc[j] = 0.f;
    for (int kb = 0; kb < 16; ++kb) {
        float4 v = x4[kb];
        float xr[4] = {v.x, v.y, v.z, v.w};
        const float* w = Wm1 + 4096 + kb * 256;
#pragma unroll
        for (int kk = 0; kk < 4; ++kk)
#pragma unroll
            for (int j = 0; j < 64; ++j) acc[j] += xr[kk] * w[kk * 64 + j];
    }
    float4* oB = (float4*)(B + (size_t)n * 64);
#pragma unroll
    for (int jq = 0; jq < 16; ++jq)
        oB[jq] = make_float4(acc[jq * 4], acc[jq * 4 + 1], acc[jq * 4 + 2], acc[jq * 4 + 3]);
}

// aggr[n] = sum_{e: tgt=n} ( relu(A[src] + B[n] + bm1) @ Wm2 + bm2 )  — 4 lanes/node
__global__ __launch_bounds__(256) void k_agg_tgt(
    const int* __restrict__ order, const int* __restrict__ deg, const int* __restrict__ off,
    const int* __restrict__ perm, const int* __restrict__ src_idx,
    const float* __restrict__ A, const float* __restrict__ B,
    const float* __restrict__ bm1, const float* __restrict__ Wm2, const float* __restrict__ bm2,
    float* __restrict__ aggr) {
    int i = blockIdx.x * 256 + threadIdx.x;
    if (i >= 4 * N_NODES) return;
    int q = i & 3;
    int n = order[i >> 2];
    int d = deg[n], base = off[n];
    float acc[64];
#pragma unroll
    for (int j = 0; j < 64; ++j) acc[j] = 0.f;
    const float4* B4 = (const float4*)(B + (size_t)n * 64);
    for (int p = q; p < d; p += 4) {
        int e = perm[base + p];
        int s = src_idx[e];
        const float4* A4 = (const float4*)(A + (size_t)s * 64);
#pragma unroll
        for (int kb = 0; kb < 16; ++kb) {
            float4 av = A4[kb], bv = B4[kb];
            float ar[4] = {av.x, av.y, av.z, av.w};
            float br[4] = {bv.x, bv.y, bv.z, bv.w};
            float h[4];
#pragma unroll
            for (int kk = 0; kk < 4; ++kk)
                h[kk] = fmaxf(bm1[kb * 4 + kk] + ar[kk] + br[kk], 0.f);
            const float* w = Wm2 + kb * 256;
#pragma unroll
            for (int kk = 0; kk < 4; ++kk)
#pragma unroll
                for (int j = 0; j < 64; ++j) acc[j] += h[kk] * w[kk * 64 + j];
        }
    }
#pragma unroll
    for (int j = 0; j < 64; ++j) {
        float v = acc[j];
        v += __shfl_xor(v, 1);
        v += __shfl_xor(v, 2);
        acc[j] = v;
    }
    if (q == 0) {
        float dd = (float)d;
        float4* o4 = (float4*)(aggr + (size_t)n * 64);
#pragma unroll
        for (int jq = 0; jq < 16; ++jq)
            o4[jq] = make_float4(acc[jq * 4 + 0] + dd * bm2[jq * 4 + 0],
                                 acc[jq * 4 + 1] + dd * bm2[jq * 4 + 1],
                                 acc[jq * 4 + 2] + dd * bm2[jq * 4 + 2],
                                 acc[jq * 4 + 3] + dd * bm2[jq * 4 + 3]);
    }
}

// ---------------- node update + decoder + head + history roll ----------------
#define BLK 128
__global__ __launch_bounds__(BLK) void k_node(
    const float* __restrict__ coded_x, const float* __restrict__ aggr,
    const float* __restrict__ Wu1, const float* __restrict__ bu1,
    const float* __restrict__ Wu2, const float* __restrict__ bu2,
    const float* __restrict__ Wd1, const float* __restrict__ bd1,
    const float* __restrict__ Wd2, const float* __restrict__ bd2,
    const float* __restrict__ h0s, const float* __restrict__ elev,
    const float* __restrict__ gl,
    float* __restrict__ h0d, float* __restrict__ out, int step) {
    __shared__ float stage[64 * BLK];
    int tid = threadIdx.x;
    int n = blockIdx.x * BLK + tid;
    bool act = n < N_NODES;
    int nn = act ? n : 0;
    const float4* xc = (const float4*)(coded_x + (size_t)nn * 64);
    const float4* xa = (const float4*)(aggr + (size_t)nn * 64);

    float acc[64];
#pragma unroll
    for (int j = 0; j < 64; ++j) acc[j] = bu1[j];
    for (int kb = 0; kb < 16; ++kb) {
        float4 v = xc[kb];
        float x[4] = {v.x, v.y, v.z, v.w};
        const float* w = Wu1 + kb * 4 * 64;
#pragma unroll
        for (int kk = 0; kk < 4; ++kk)
#pragma unroll
            for (int j = 0; j < 64; ++j) acc[j] += x[kk] * w[kk * 64 + j];
    }
    for (int kb = 0; kb < 16; ++kb) {
        float4 v = xa[kb];
        float x[4] = {v.x, v.y, v.z, v.w};
        const float* w = Wu1 + (64 + kb * 4) * 64;
#pragma unroll
        for (int kk = 0; kk < 4; ++kk)
#pragma unroll
            for (int j = 0; j < 64; ++j) acc[j] += x[kk] * w[kk * 64 + j];
    }
#pragma unroll
    for (int k = 0; k < 64; ++k) stage[k * BLK + tid] = fmaxf(acc[k], 0.f);

    float acc2[64];
#pragma unroll
    for (int j = 0; j < 64; ++j) acc2[j] = bu2[j];
    for (int kb = 0; kb < 16; ++kb) {
        float h[4];
#pragma unroll
        for (int kk = 0; kk < 4; ++kk) h[kk] = stage[(kb * 4 + kk) * BLK + tid];
        const float* w = Wu2 + kb * 4 * 64;
#pragma unroll
        for (int kk = 0; kk < 4; ++kk)
#pragma unroll
            for (int j = 0; j < 64; ++j) acc2[j] += h[kk] * w[kk * 64 + j];
    }
#pragma unroll
    for (int k = 0; k < 64; ++k) stage[k * BLK + tid] = acc2[k];
#pragma unroll
    for (int j = 0; j < 64; ++j) acc[j] = bd1[j];
    for (int kb = 0; kb < 16; ++kb) {
        float h[4];
#pragma unroll
        for (int kk = 0; kk < 4; ++kk) h[kk] = stage[(kb * 4 + kk) * BLK + tid];
        const float* w = Wd1 + kb * 4 * 64;
#pragma unroll
        for (int kk = 0; kk < 4; ++kk)
#pragma unroll
            for (int j = 0; j < 64; ++j) acc[j] += h[kk] * w[kk * 64 + j];
    }
#pragma unroll
    for (int k = 0; k < 64; ++k) stage[k * BLK + tid] = fmaxf(acc[k], 0.f);
    float dec[4];
#pragma unroll
    for (int j = 0; j < 4; ++j) dec[j] = bd2[j];
    for (int kb = 0; kb < 16; ++kb) {
        float h[4];
#pragma unroll
        for (int kk = 0; kk < 4; ++kk) h[kk] = stage[(kb * 4 + kk) * BLK + tid];
        const float* w = Wd2 + kb * 4 * 4;
#pragma unroll
        for (int kk = 0; kk < 4; ++kk)
#pragma unroll
            for (int j = 0; j < 4; ++j) dec[j] += h[kk] * w[kk * 4 + j];
    }

    if (act) {
        float el = elev[n], g = gl[n];
        float prev = h0s[(size_t)n * 8 + 7] - el;
        float h4 = h0s[(size_t)n * 8 + 4], h5 = h0s[(size_t)n * 8 + 5],
              h6 = h0s[(size_t)n * 8 + 6], h7 = h0s[(size_t)n * 8 + 7];
        float pc[4];
#pragma unroll
        for (int j = 0; j < 4; ++j) {
            float ph = 0.5f * dec[j] + 0.5f * prev + el;
            pc[j] = fminf(ph, g);
            out[(size_t)n * 16 + step + j] = fmaxf(pc[j], el);
        }
        h0d[(size_t)n * 8 + 0] = h4;
        h0d[(size_t)n * 8 + 1] = h5;
        h0d[(size_t)n * 8 + 2] = h6;
        h0d[(size_t)n * 8 + 3] = h7;
#pragma unroll
        for (int j = 0; j < 4; ++j) h0d[(size_t)n * 8 + 4 + j] = pc[j];
    }
}

extern "C" void kernel_launch(void* const* d_in, const int* in_sizes, int n_in,
                              void* d_out, int out_size, void* d_ws, size_t ws_size,
                              hipStream_t stream) {
    const float* h0     = (const float*)d_in[0];
    const float* runoff = (const float*)d_in[1];
    const float* elev   = (const float*)d_in[2];
    const float* gl     = (const float*)d_in[3];
    const float* efeat  = (const float*)d_in[4];
    const int*   ei     = (const int*)d_in[5];
    const float *We1 = (const float*)d_in[7],  *be1 = (const float*)d_in[8];
    const float *We2 = (const float*)d_in[9],  *be2 = (const float*)d_in[10];
    const float *Wm1 = (const float*)d_in[11], *bm1 = (const float*)d_in[12];
    const float *Wm2 = (const float*)d_in[13], *bm2 = (const float*)d_in[14];
    const float *Wu1 = (const float*)d_in[15], *bu1 = (const float*)d_in[16];
    const float *Wu2 = (const float*)d_in[17], *bu2 = (const float*)d_in[18];
    const float *Wd1 = (const float*)d_in[19], *bd1 = (const float*)d_in[20];
    const float *Wd2 = (const float*)d_in[21], *bd2 = (const float*)d_in[22];
    float* out = (float*)d_out;

    // ---- workspace layout ----
    float* F = (float*)d_ws;
    float* S   = F;                     // 100k*64  (reused as A)
    float* T   = S + 6400000;           // 100k*64  (reused as B)
    float* cx  = T + 6400000;
    float* ag  = cx + 6400000;
    float* h0A = ag + 6400000;
    float* h0B = h0A + 800000;
    int* I = (int*)(h0B + 800000);
    int* deg_src  = I;
    int* deg_tgt  = I + 100000;
    int* cur_src  = I + 200000;
    int* cur_tgt  = I + 300000;
    int* off_src  = I + 400000;
    int* off_tgt  = I + 500000;
    int* perm_src = I + 600000;
    int* perm_tgt = I + 1400000;
    int* order_src= I + 2200000;
    int* order_tgt= I + 2300000;
    int* bsum     = I + 2400000;        // 512
    int* bh       = I + 2400512;        // 391*128 = 50048
    int* doff     = I + 2450560;        // 128

    const int* src = ei;
    const int* tgt = ei + N_EDGES;

    int nb = (N_NODES + 255) / 256;    // 391

    // ---- once per launch: CSR + degree-sorted orders (no contended atomics) ----
    hipMemsetAsync(I, 0, (size_t)400000 * sizeof(int), stream);   // deg_*, cur_*
    k_hist<<<(N_EDGES + 255) / 256, 256, 0, stream>>>(src, tgt, deg_src, deg_tgt);

    k_scan1<<<nb, 256, 0, stream>>>(deg_src, off_src, bsum, N_NODES);
    k_scan_top<<<1, 512, 0, stream>>>(bsum, nb);
    k_scan_add<<<nb, 256, 0, stream>>>(off_src, bsum, N_NODES);
    k_scan1<<<nb, 256, 0, stream>>>(deg_tgt, off_tgt, bsum, N_NODES);
    k_scan_top<<<1, 512, 0, stream>>>(bsum, nb);
    k_scan_add<<<nb, 256, 0, stream>>>(off_tgt, bsum, N_NODES);

    k_fill<<<(N_EDGES + 255) / 256, 256, 0, stream>>>(src, tgt, off_src, off_tgt,
                                                      cur_src, cur_tgt, perm_src, perm_tgt);
    k_blockhist<<<nb, 256, 0, stream>>>(deg_src, deg_tgt, bh);
    k_binscan<<<1, 128, 0, stream>>>(bh, doff, nb);
    k_fill_order2<<<nb, 256, 0, stream>>>(deg_src, deg_tgt, bh, doff, order_src, order_tgt);

    // ---- 4 prediction steps ----
    const float* h0rd[4] = {h0, h0A, h0B, h0A};
    float*       h0wr[4] = {h0A, h0B, h0A, h0B};
    int nag = (4 * N_NODES + 255) / 256;   // 1563

    for (int st = 0; st < 4; ++st) {
        int step = st * 4;
        k_pre_enc<<<nb, 256, 0, stream>>>(h0rd[st], runoff, elev, We1, S, T, step);
        k_agg_src<<<nag, 256, 0, stream>>>(order_src, deg_src, off_src, perm_src, tgt, efeat,
                                           S, T, We1, be1, We2, be2, cx);
        k_pre_msg<<<nb, 256, 0, stream>>>(cx, Wm1, S, T);   // S=A, T=B (reuse)
        k_agg_tgt<<<nag, 256, 0, stream>>>(order_tgt, deg_tgt, off_tgt, perm_tgt, src,
                                           S, T, bm1, Wm2, bm2, ag);
        k_node<<<(N_NODES + BLK - 1) / BLK, BLK, 0, stream>>>(
            cx, ag, Wu1, bu1, Wu2, bu2, Wd1, bd1, Wd2, bd2,
            h0rd[st], elev, gl, h0wr[st], out, step);
    }
}

// Round 9
// 2377.511 us; speedup vs baseline: 9.7659x; 1.8164x over previous
//
#include <hip/hip_runtime.h>

#define N_NODES 100000
#define N_EDGES 800000

typedef __attribute__((ext_vector_type(8))) short bh8;   // 8 bf16 MFMA A/B frag
typedef __attribute__((ext_vector_type(4))) float f4;    // 4 f32 MFMA C/D frag

__device__ __forceinline__ unsigned bf16_1(float a) {    // f32 -> bf16 bits (RNE), low 16
    unsigned u = __float_as_uint(a);
    return (u + 0x7fffu + ((u >> 16) & 1u)) >> 16;
}
__device__ __forceinline__ float ubf(unsigned u16) { return __uint_as_float(u16 << 16); }

// ============================ setup: CSR build ============================

__global__ __launch_bounds__(256) void k_hist(const int* __restrict__ src, const int* __restrict__ tgt,
                                              int* __restrict__ deg_src, int* __restrict__ deg_tgt) {
    int e = blockIdx.x * 256 + threadIdx.x;
    if (e >= N_EDGES) return;
    atomicAdd(&deg_src[src[e]], 1);
    atomicAdd(&deg_tgt[tgt[e]], 1);
}

__global__ __launch_bounds__(256) void k_scan1(const int* __restrict__ in, int* __restrict__ out,
                                               int* __restrict__ bsum, int n) {
    __shared__ int sm[256];
    int tid = threadIdx.x;
    int i = blockIdx.x * 256 + tid;
    int v = (i < n) ? in[i] : 0;
    int acc = v;
    sm[tid] = acc; __syncthreads();
    for (int d = 1; d < 256; d <<= 1) {
        int o = (tid >= d) ? sm[tid - d] : 0;
        __syncthreads();
        acc += o; sm[tid] = acc;
        __syncthreads();
    }
    if (i < n) out[i] = acc - v;
    if (tid == 255) bsum[blockIdx.x] = acc;
}

__global__ __launch_bounds__(512) void k_scan_top(int* __restrict__ a, int n) {
    __shared__ int sm[512];
    int tid = threadIdx.x;
    int v = (tid < n) ? a[tid] : 0;
    int acc = v;
    sm[tid] = acc; __syncthreads();
    for (int d = 1; d < 512; d <<= 1) {
        int o = (tid >= d) ? sm[tid - d] : 0;
        __syncthreads();
        acc += o; sm[tid] = acc;
        __syncthreads();
    }
    if (tid < n) a[tid] = acc - v;
}

__global__ __launch_bounds__(256) void k_scan_add(int* __restrict__ out, const int* __restrict__ bsum, int n) {
    int i = blockIdx.x * 256 + threadIdx.x;
    if (i < n) out[i] += bsum[blockIdx.x];
}

__global__ __launch_bounds__(256) void k_fill(const int* __restrict__ src, const int* __restrict__ tgt,
                                              const int* __restrict__ off_src, const int* __restrict__ off_tgt,
                                              int* __restrict__ cur_src, int* __restrict__ cur_tgt,
                                              int* __restrict__ perm_src, int* __restrict__ tgt_ps,
                                              int* __restrict__ p2n_src, int* __restrict__ src_pt,
                                              int* __restrict__ p2n_tgt) {
    int e = blockIdx.x * 256 + threadIdx.x;
    if (e >= N_EDGES) return;
    int s = src[e], t = tgt[e];
    int r1 = atomicAdd(&cur_src[s], 1);
    int ps = off_src[s] + r1;
    perm_src[ps] = e; tgt_ps[ps] = t; p2n_src[ps] = s;
    int r2 = atomicAdd(&cur_tgt[t], 1);
    int pt = off_tgt[t] + r2;
    src_pt[pt] = s; p2n_tgt[pt] = t;
}

// ============================ per-step kernels ============================

// S[n] = nf[n] @ We1[3:24], T[n] = nf[n] @ We1[24:45]  (fp32 out)
__global__ __launch_bounds__(256) void k_pre_enc(const float* __restrict__ h0, const float* __restrict__ runoff,
                                                 const float* __restrict__ elev, const float* __restrict__ We1,
                                                 float* __restrict__ S, float* __restrict__ T, int step) {
    int n = blockIdx.x * 256 + threadIdx.x;
    if (n >= N_NODES) return;
    float x[21];
    const float4* h4 = (const float4*)(h0 + (size_t)n * 8);
    float4 a = h4[0], b = h4[1];
    x[0] = a.x; x[1] = a.y; x[2] = a.z; x[3] = a.w;
    x[4] = b.x; x[5] = b.y; x[6] = b.z; x[7] = b.w;
    const float4* r4 = (const float4*)(runoff + (size_t)n * 24 + step);
    float4 r0 = r4[0], r1 = r4[1], r2 = r4[2];
    x[8] = r0.x;  x[9] = r0.y;  x[10] = r0.z; x[11] = r0.w;
    x[12] = r1.x; x[13] = r1.y; x[14] = r1.z; x[15] = r1.w;
    x[16] = r2.x; x[17] = r2.y; x[18] = r2.z; x[19] = r2.w;
    x[20] = elev[n];
    for (int jq = 0; jq < 16; ++jq) {
        float s0 = 0, s1 = 0, s2 = 0, s3 = 0, t0 = 0, t1 = 0, t2 = 0, t3 = 0;
#pragma unroll
        for (int k = 0; k < 21; ++k) {
            float xv = x[k];
            const float* wS = We1 + (3 + k) * 64 + jq * 4;
            const float* wT = We1 + (24 + k) * 64 + jq * 4;
            s0 += xv * wS[0]; s1 += xv * wS[1]; s2 += xv * wS[2]; s3 += xv * wS[3];
            t0 += xv * wT[0]; t1 += xv * wT[1]; t2 += xv * wT[2]; t3 += xv * wT[3];
        }
        *(float4*)(S + (size_t)n * 64 + jq * 4) = make_float4(s0, s1, s2, s3);
        *(float4*)(T + (size_t)n * 64 + jq * 4) = make_float4(t0, t1, t2, t3);
    }
}

// A[n] = cx[n] @ Wm1[0:64], B[n] = cx[n] @ Wm1[64:128]  (fp32 out)
__global__ __launch_bounds__(256) void k_pre_msg(const float* __restrict__ cx, const float* __restrict__ Wm1,
                                                 float* __restrict__ A, float* __restrict__ B) {
    int n = blockIdx.x * 256 + threadIdx.x;
    if (n >= N_NODES) return;
    const float4* x4 = (const float4*)(cx + (size_t)n * 64);
    float acc[64];
#pragma unroll
    for (int j = 0; j < 64; ++j) acc[j] = 0.f;
    for (int kb = 0; kb < 16; ++kb) {
        float4 v = x4[kb];
        float xr[4] = {v.x, v.y, v.z, v.w};
        const float* w = Wm1 + kb * 256;
#pragma unroll
        for (int kk = 0; kk < 4; ++kk)
#pragma unroll
            for (int j = 0; j < 64; ++j) acc[j] += xr[kk] * w[kk * 64 + j];
    }
    float4* oA = (float4*)(A + (size_t)n * 64);
#pragma unroll
    for (int jq = 0; jq < 16; ++jq)
        oA[jq] = make_float4(acc[jq * 4], acc[jq * 4 + 1], acc[jq * 4 + 2], acc[jq * 4 + 3]);
#pragma unroll
    for (int j = 0; j < 64; ++j) acc[j] = 0.f;
    for (int kb = 0; kb < 16; ++kb) {
        float4 v = x4[kb];
        float xr[4] = {v.x, v.y, v.z, v.w};
        const float* w = Wm1 + 4096 + kb * 256;
#pragma unroll
        for (int kk = 0; kk < 4; ++kk)
#pragma unroll
            for (int j = 0; j < 64; ++j) acc[j] += xr[kk] * w[kk * 64 + j];
    }
    float4* oB = (float4*)(B + (size_t)n * 64);
#pragma unroll
    for (int jq = 0; jq < 16; ++jq)
        oB[jq] = make_float4(acc[jq * 4], acc[jq * 4 + 1], acc[jq * 4 + 2], acc[jq * 4 + 3]);
}

// ---------------- MFMA edge-tile agg, bf16x3 split + fp32 C path ----------------
// LDS: Wh [0,8K); Wl [8K,16K); H1 [16K,48K) (hi pass then lo restage); p2n [48K,49K);
// fp32 C overlay [0,33280) in two 32-col passes after all B/H1 reads complete.
#define SMB_LO 8192
#define SMH 16384
#define SMP 49152
#define CSTR_F 1040

template<int HAS_EF>
__global__ __launch_bounds__(256) void k_agg3(
    const int* __restrict__ permE, const int* __restrict__ otherI,
    const int* __restrict__ p2n,
    const int* __restrict__ off, const int* __restrict__ deg,
    const float* __restrict__ efeat,
    const float* __restrict__ X, const float* __restrict__ Y,
    const float* __restrict__ W1e, const float* __restrict__ b1,
    const float* __restrict__ W2, const float* __restrict__ b2,
    float* __restrict__ outx)
{
    __shared__ alignas(16) char sm[50176];
    const int tid = threadIdx.x;
    const int pos = blockIdx.x * 256 + tid;

    *(int*)(sm + SMP + tid * 4) = p2n[pos];

    // stage W2 hi/lo bf16 fragments: W2[k][col] -> slot(nt,kt,kg,c0,i)
    for (int idx = tid; idx < 4096; idx += 256) {
        int k = idx >> 6, col = idx & 63;
        float wv = W2[idx];
        unsigned h16 = bf16_1(wv);
        unsigned l16 = bf16_1(wv - ubf(h16));
        int nt = col >> 4, c0 = col & 15, kt = k >> 5, kg = (k >> 3) & 3, i = k & 7;
        int o = (nt * 2 + kt) * 1024 + (kg * 16 + c0) * 16 + i * 2;
        *(unsigned short*)(sm + o) = (unsigned short)h16;
        *(unsigned short*)(sm + SMB_LO + o) = (unsigned short)l16;
    }

    // ---- phase 1: fp32 gather + layer1 + hi/lo split; stage hi, keep lo in regs ----
    int own = p2n[pos];
    int oth = otherI[pos];
    float ef0 = 0.f, ef1 = 0.f, ef2 = 0.f;
    if (HAS_EF) { int e = permE[pos]; ef0 = efeat[3 * e]; ef1 = efeat[3 * e + 1]; ef2 = efeat[3 * e + 2]; }
    const float4* Xu = (const float4*)(X + (size_t)own * 64);
    const float4* Yu = (const float4*)(Y + (size_t)oth * 64);
    char* hb = sm + SMH + (tid >> 6) * 8192 + ((tid >> 4) & 3) * 2048 + (tid & 15) * 16;
    uint4 lop[8];
#pragma unroll
    for (int g = 0; g < 8; ++g) {
        float4 xa = Xu[2 * g], xb = Xu[2 * g + 1], ya = Yu[2 * g], yb = Yu[2 * g + 1];
        float hv[8];
        hv[0] = xa.x + ya.x; hv[1] = xa.y + ya.y; hv[2] = xa.z + ya.z; hv[3] = xa.w + ya.w;
        hv[4] = xb.x + yb.x; hv[5] = xb.y + yb.y; hv[6] = xb.z + yb.z; hv[7] = xb.w + yb.w;
#pragma unroll
        for (int j = 0; j < 8; ++j) {
            int k = g * 8 + j;
            float v = hv[j] + b1[k];
            if (HAS_EF) v += ef0 * W1e[k] + ef1 * W1e[64 + k] + ef2 * W1e[128 + k];
            hv[j] = fmaxf(v, 0.f);
        }
        unsigned hi[4], lo[4];
#pragma unroll
        for (int p = 0; p < 4; ++p) {
            unsigned ha = bf16_1(hv[2 * p]), hb2 = bf16_1(hv[2 * p + 1]);
            float la = hv[2 * p] - ubf(ha), lb = hv[2 * p + 1] - ubf(hb2);
            hi[p] = ha | (hb2 << 16);
            lo[p] = bf16_1(la) | (bf16_1(lb) << 16);
        }
        int kt = g >> 2, kg = g & 3;
        *(uint4*)(hb + kt * 1024 + kg * 256) = make_uint4(hi[0], hi[1], hi[2], hi[3]);
        lop[g] = make_uint4(lo[0], lo[1], lo[2], lo[3]);
    }
    __syncthreads();                                    // (1) hi + W staged

    // ---- phase 2 pass 1: Ah*Wh + Ah*Wl ----
    const int w = tid >> 6, l = tid & 63;
    bh8 bh_[4][2], bl_[4][2];
#pragma unroll
    for (int nt = 0; nt < 4; ++nt)
#pragma unroll
        for (int kt = 0; kt < 2; ++kt) {
            bh_[nt][kt] = *(const bh8*)(sm + (nt * 2 + kt) * 1024 + l * 16);
            bl_[nt][kt] = *(const bh8*)(sm + SMB_LO + (nt * 2 + kt) * 1024 + l * 16);
        }
    f4 acc[4][4];
#pragma unroll
    for (int nt = 0; nt < 4; ++nt) {
        float bv = b2[nt * 16 + (l & 15)];
        f4 ci = {bv, bv, bv, bv};
#pragma unroll
        for (int mt = 0; mt < 4; ++mt) acc[mt][nt] = ci;
    }
    const char* ab = sm + SMH + w * 8192;
#pragma unroll
    for (int mt = 0; mt < 4; ++mt) {
        bh8 a0 = *(const bh8*)(ab + mt * 2048 + l * 16);
        bh8 a1 = *(const bh8*)(ab + mt * 2048 + 1024 + l * 16);
#pragma unroll
        for (int nt = 0; nt < 4; ++nt) {
            acc[mt][nt] = __builtin_amdgcn_mfma_f32_16x16x32_bf16(a0, bh_[nt][0], acc[mt][nt], 0, 0, 0);
            acc[mt][nt] = __builtin_amdgcn_mfma_f32_16x16x32_bf16(a1, bh_[nt][1], acc[mt][nt], 0, 0, 0);
            acc[mt][nt] = __builtin_amdgcn_mfma_f32_16x16x32_bf16(a0, bl_[nt][0], acc[mt][nt], 0, 0, 0);
            acc[mt][nt] = __builtin_amdgcn_mfma_f32_16x16x32_bf16(a1, bl_[nt][1], acc[mt][nt], 0, 0, 0);
        }
    }
    __syncthreads();                                    // (2) pass-1 reads done
    // restage lo into the same H1 slots
#pragma unroll
    for (int g = 0; g < 8; ++g) {
        int kt = g >> 2, kg = g & 3;
        *(uint4*)(hb + kt * 1024 + kg * 256) = lop[g];
    }
    __syncthreads();                                    // (3) lo staged
    // ---- phase 2 pass 2: Al*Wh ----
#pragma unroll
    for (int mt = 0; mt < 4; ++mt) {
        bh8 a0 = *(const bh8*)(ab + mt * 2048 + l * 16);
        bh8 a1 = *(const bh8*)(ab + mt * 2048 + 1024 + l * 16);
#pragma unroll
        for (int nt = 0; nt < 4; ++nt) {
            acc[mt][nt] = __builtin_amdgcn_mfma_f32_16x16x32_bf16(a0, bh_[nt][0], acc[mt][nt], 0, 0, 0);
            acc[mt][nt] = __builtin_amdgcn_mfma_f32_16x16x32_bf16(a1, bh_[nt][1], acc[mt][nt], 0, 0, 0);
        }
    }
    __syncthreads();                                    // (4) all LDS A/B reads done

    // ---- phase 3: fp32 C via LDS, two 32-col passes; interior store / boundary atomicAdd ----
    // C map (m89): col = lane&15 (+nt*16), row = (lane>>4)*4 + reg (+mt*16, +w*64)
#pragma unroll
    for (int pass = 0; pass < 2; ++pass) {
#pragma unroll
        for (int mt = 0; mt < 4; ++mt)
#pragma unroll
            for (int ntl = 0; ntl < 2; ++ntl) {
                int nt = pass * 2 + ntl;
                int col32 = ntl * 16 + (l & 15);
                int row0 = w * 64 + mt * 16 + (l >> 4) * 4;
                *(float4*)(sm + col32 * CSTR_F + row0 * 4) =
                    make_float4(acc[mt][nt][0], acc[mt][nt][1], acc[mt][nt][2], acc[mt][nt][3]);
            }
        __syncthreads();
        {
            int col32 = tid & 31, seg = tid >> 5;        // 8 segs x 32 edges
            int col = pass * 32 + col32;
            int gb = blockIdx.x * 256 + seg * 32;
            const char* cr = sm + col32 * CSTR_F + seg * 128;
            const int* lp2n = (const int*)(sm + SMP) + seg * 32;
            float a = 0.f;
            int cur = lp2n[0];
            for (int c4 = 0; c4 < 8; ++c4) {
                float4 v = *(const float4*)(cr + c4 * 16);
                float ff[4] = {v.x, v.y, v.z, v.w};
#pragma unroll
                for (int j = 0; j < 4; ++j) {
                    int nd = lp2n[c4 * 4 + j];
                    if (nd != cur) {
                        int o = off[cur], dgg = deg[cur];
                        if (o >= gb && o + dgg <= gb + 32) outx[(size_t)cur * 64 + col] = a;
                        else atomicAdd(&outx[(size_t)cur * 64 + col], a);
                        a = 0.f; cur = nd;
                    }
                    a += ff[j];
                }
            }
            int o = off[cur], dgg = deg[cur];
            if (o >= gb && o + dgg <= gb + 32) outx[(size_t)cur * 64 + col] = a;
            else atomicAdd(&outx[(size_t)cur * 64 + col], a);
        }
        __syncthreads();                                 // C region reused by next pass
    }
}

// ---------------- node update + decoder + head + history roll (fp32) ----------------
#define BLK 128
__global__ __launch_bounds__(BLK) void k_node(
    const float* __restrict__ coded_x, const float* __restrict__ aggr,
    const float* __restrict__ Wu1, const float* __restrict__ bu1,
    const float* __restrict__ Wu2, const float* __restrict__ bu2,
    const float* __restrict__ Wd1, const float* __restrict__ bd1,
    const float* __restrict__ Wd2, const float* __restrict__ bd2,
    const float* __restrict__ h0s, const float* __restrict__ elev,
    const float* __restrict__ gl,
    float* __restrict__ h0d, float* __restrict__ out, int step) {
    __shared__ float stage[64 * BLK];
    int tid = threadIdx.x;
    int n = blockIdx.x * BLK + tid;
    bool act = n < N_NODES;
    int nn = act ? n : 0;
    const float4* xc = (const float4*)(coded_x + (size_t)nn * 64);
    const float4* xa = (const float4*)(aggr + (size_t)nn * 64);

    float acc[64];
#pragma unroll
    for (int j = 0; j < 64; ++j) acc[j] = bu1[j];
    for (int kb = 0; kb < 16; ++kb) {
        float4 v = xc[kb];
        float x[4] = {v.x, v.y, v.z, v.w};
        const float* w = Wu1 + kb * 4 * 64;
#pragma unroll
        for (int kk = 0; kk < 4; ++kk)
#pragma unroll
            for (int j = 0; j < 64; ++j) acc[j] += x[kk] * w[kk * 64 + j];
    }
    for (int kb = 0; kb < 16; ++kb) {
        float4 v = xa[kb];
        float x[4] = {v.x, v.y, v.z, v.w};
        const float* w = Wu1 + (64 + kb * 4) * 64;
#pragma unroll
        for (int kk = 0; kk < 4; ++kk)
#pragma unroll
            for (int j = 0; j < 64; ++j) acc[j] += x[kk] * w[kk * 64 + j];
    }
#pragma unroll
    for (int k = 0; k < 64; ++k) stage[k * BLK + tid] = fmaxf(acc[k], 0.f);

    float acc2[64];
#pragma unroll
    for (int j = 0; j < 64; ++j) acc2[j] = bu2[j];
    for (int kb = 0; kb < 16; ++kb) {
        float h[4];
#pragma unroll
        for (int kk = 0; kk < 4; ++kk) h[kk] = stage[(kb * 4 + kk) * BLK + tid];
        const float* w = Wu2 + kb * 4 * 64;
#pragma unroll
        for (int kk = 0; kk < 4; ++kk)
#pragma unroll
            for (int j = 0; j < 64; ++j) acc2[j] += h[kk] * w[kk * 64 + j];
    }
#pragma unroll
    for (int k = 0; k < 64; ++k) stage[k * BLK + tid] = acc2[k];
#pragma unroll
    for (int j = 0; j < 64; ++j) acc[j] = bd1[j];
    for (int kb = 0; kb < 16; ++kb) {
        float h[4];
#pragma unroll
        for (int kk = 0; kk < 4; ++kk) h[kk] = stage[(kb * 4 + kk) * BLK + tid];
        const float* w = Wd1 + kb * 4 * 64;
#pragma unroll
        for (int kk = 0; kk < 4; ++kk)
#pragma unroll
            for (int j = 0; j < 64; ++j) acc[j] += h[kk] * w[kk * 64 + j];
    }
#pragma unroll
    for (int k = 0; k < 64; ++k) stage[k * BLK + tid] = fmaxf(acc[k], 0.f);
    float dec[4];
#pragma unroll
    for (int j = 0; j < 4; ++j) dec[j] = bd2[j];
    for (int kb = 0; kb < 16; ++kb) {
        float h[4];
#pragma unroll
        for (int kk = 0; kk < 4; ++kk) h[kk] = stage[(kb * 4 + kk) * BLK + tid];
        const float* w = Wd2 + kb * 4 * 4;
#pragma unroll
        for (int kk = 0; kk < 4; ++kk)
#pragma unroll
            for (int j = 0; j < 4; ++j) dec[j] += h[kk] * w[kk * 4 + j];
    }

    if (act) {
        float el = elev[n], g = gl[n];
        float prev = h0s[(size_t)n * 8 + 7] - el;
        float h4 = h0s[(size_t)n * 8 + 4], h5 = h0s[(size_t)n * 8 + 5],
              h6 = h0s[(size_t)n * 8 + 6], h7 = h0s[(size_t)n * 8 + 7];
        float pc[4];
#pragma unroll
        for (int j = 0; j < 4; ++j) {
            float ph = 0.5f * dec[j] + 0.5f * prev + el;
            pc[j] = fminf(ph, g);
            out[(size_t)n * 16 + step + j] = fmaxf(pc[j], el);
        }
        h0d[(size_t)n * 8 + 0] = h4;
        h0d[(size_t)n * 8 + 1] = h5;
        h0d[(size_t)n * 8 + 2] = h6;
        h0d[(size_t)n * 8 + 3] = h7;
#pragma unroll
        for (int j = 0; j < 4; ++j) h0d[(size_t)n * 8 + 4 + j] = pc[j];
    }
}

extern "C" void kernel_launch(void* const* d_in, const int* in_sizes, int n_in,
                              void* d_out, int out_size, void* d_ws, size_t ws_size,
                              hipStream_t stream) {
    const float* h0     = (const float*)d_in[0];
    const float* runoff = (const float*)d_in[1];
    const float* elev   = (const float*)d_in[2];
    const float* gl     = (const float*)d_in[3];
    const float* efeat  = (const float*)d_in[4];
    const int*   ei     = (const int*)d_in[5];
    const float *We1 = (const float*)d_in[7],  *be1 = (const float*)d_in[8];
    const float *We2 = (const float*)d_in[9],  *be2 = (const float*)d_in[10];
    const float *Wm1 = (const float*)d_in[11], *bm1 = (const float*)d_in[12];
    const float *Wm2 = (const float*)d_in[13], *bm2 = (const float*)d_in[14];
    const float *Wu1 = (const float*)d_in[15], *bu1 = (const float*)d_in[16];
    const float *Wu2 = (const float*)d_in[17], *bu2 = (const float*)d_in[18];
    const float *Wd1 = (const float*)d_in[19], *bd1 = (const float*)d_in[20];
    const float *Wd2 = (const float*)d_in[21], *bd2 = (const float*)d_in[22];
    float* out = (float*)d_out;

    // ---- workspace layout ----
    float* F   = (float*)d_ws;
    float* S   = F;                     // 6.4M f32 (reused as A)
    float* T   = S + 6400000;           // 6.4M f32 (reused as B)
    float* cx  = T + 6400000;
    float* ag  = cx + 6400000;          // adjacent to cx: single memset
    float* h0A = ag + 6400000;
    float* h0B = h0A + 800000;
    int* I = (int*)(h0B + 800000);
    int* deg_src  = I;
    int* deg_tgt  = I + 100000;
    int* cur_src  = I + 200000;
    int* cur_tgt  = I + 300000;
    int* off_src  = I + 400000;
    int* off_tgt  = I + 500000;
    int* perm_src = I + 600000;     // 800k
    int* tgt_ps   = I + 1400000;    // 800k
    int* p2n_src  = I + 2200000;    // 800k
    int* src_pt   = I + 3000000;    // 800k
    int* p2n_tgt  = I + 3800000;    // 800k
    int* bsum     = I + 4600000;    // 512

    const int* src = ei;
    const int* tgt = ei + N_EDGES;
    int nb = (N_NODES + 255) / 256;          // 391
    int ne = (N_EDGES + 255) / 256;          // 3125

    // ---- setup: CSR (both orders) ----
    hipMemsetAsync(I, 0, (size_t)400000 * sizeof(int), stream);   // deg_*, cur_*
    k_hist<<<ne, 256, 0, stream>>>(src, tgt, deg_src, deg_tgt);
    k_scan1<<<nb, 256, 0, stream>>>(deg_src, off_src, bsum, N_NODES);
    k_scan_top<<<1, 512, 0, stream>>>(bsum, nb);
    k_scan_add<<<nb, 256, 0, stream>>>(off_src, bsum, N_NODES);
    k_scan1<<<nb, 256, 0, stream>>>(deg_tgt, off_tgt, bsum, N_NODES);
    k_scan_top<<<1, 512, 0, stream>>>(bsum, nb);
    k_scan_add<<<nb, 256, 0, stream>>>(off_tgt, bsum, N_NODES);
    k_fill<<<ne, 256, 0, stream>>>(src, tgt, off_src, off_tgt, cur_src, cur_tgt,
                                   perm_src, tgt_ps, p2n_src, src_pt, p2n_tgt);

    // ---- 4 prediction steps ----
    const float* h0rd[4] = {h0, h0A, h0B, h0A};
    float*       h0wr[4] = {h0A, h0B, h0A, h0B};

    for (int st = 0; st < 4; ++st) {
        int step = st * 4;
        k_pre_enc<<<nb, 256, 0, stream>>>(h0rd[st], runoff, elev, We1, S, T, step);
        hipMemsetAsync(cx, 0, (size_t)12800000 * sizeof(float), stream);   // cx + ag
        // coded_x: edges sorted by src; own=src (S), other=tgt (T)
        k_agg3<1><<<ne, 256, 0, stream>>>(perm_src, tgt_ps, p2n_src, off_src, deg_src,
                                          efeat, S, T, We1, be1, We2, be2, cx);
        // A/B from cx (reuses S/T buffers)
        k_pre_msg<<<nb, 256, 0, stream>>>(cx, Wm1, S, T);   // S=A, T=B
        // aggr: edges sorted by tgt; own=tgt (B=T), other=src (A=S)
        k_agg3<0><<<ne, 256, 0, stream>>>(nullptr, src_pt, p2n_tgt, off_tgt, deg_tgt,
                                          nullptr, T, S, nullptr, bm1, Wm2, bm2, ag);
        k_node<<<(N_NODES + BLK - 1) / BLK, BLK, 0, stream>>>(
            cx, ag, Wu1, bu1, Wu2, bu2, Wd1, bd1, Wd2, bd2,
            h0rd[st], elev, gl, h0wr[st], out, step);
    }
}